// Round 6
// baseline (265.541 us; speedup 1.0000x reference)
//
#include <hip/hip_runtime.h>
#include <stdint.h>

#define DEV __device__ __forceinline__

typedef unsigned short u16;
typedef u16   u16x8 __attribute__((ext_vector_type(8)));
typedef u16   u16x4 __attribute__((ext_vector_type(4)));
typedef __bf16 bf16x8v __attribute__((ext_vector_type(8)));
typedef float f32x4 __attribute__((ext_vector_type(4)));

constexpr int NWIN = 81;          // 9x9 windows per batch
constexpr int BN   = 4 * NWIN;    // 324 total windows
constexpr float EPS = 1e-5f;
constexpr float SCALE = 0.07216878364870322f; // 192^-0.5

DEV u16 f2bf(float f) {            // fp32 -> bf16 RNE
    unsigned u = __builtin_bit_cast(unsigned, f);
    u += 0x7fffu + ((u >> 16) & 1u);
    return (u16)(u >> 16);
}

DEV f32x4 mfma16(bf16x8v a, bf16x8v b, f32x4 c) {
    return __builtin_amdgcn_mfma_f32_16x16x32_bf16(a, b, c, 0, 0, 0);
}

// ---------------- kernel 0: convert Wq|Wk|Wv fp32 -> bf16 (contiguous in ws)
__global__ void wconv(const float* __restrict__ wq, const float* __restrict__ wk,
                      const float* __restrict__ wv, u16* __restrict__ dst) {
    int idx = blockIdx.x * 256 + threadIdx.x;       // 3*36864 exact
    const float* src = (idx < 36864) ? wq : (idx < 73728 ? wk : wv);
    int r = (idx < 36864) ? idx : (idx < 73728 ? idx - 36864 : idx - 73728);
    dst[idx] = f2bf(src[r]);
}

// ---------------- kernel 1: LN stats + normalize -> lxg bf16 [b][pix][192]
// block = one (b,h) row of 128 pixels. 256 threads.
__global__ void lnx_kernel(const float* __restrict__ x, const float* __restrict__ gamma,
                           const float* __restrict__ beta, u16* __restrict__ lxg) {
    __shared__ float p1[8][132], p2[8][132];
    __shared__ float gb[384];
    __shared__ float mu_s[128], rs_s[128];
    __shared__ u16 lxs[128 * 200];

    const int bh = blockIdx.x;               // 0..511
    const int b = bh >> 7, h = bh & 127;
    const int tid = threadIdx.x;
    const int w4 = tid & 31, cg = tid >> 5;  // 32 pixel-quads x 8 channel groups

    if (tid < 192) { gb[tid] = gamma[tid]; gb[192 + tid] = beta[tid]; }

    const float* base = x + (((long)(b * 192 + cg)) * 128 + h) * 128 + 4 * w4;
    // ---- pass 1: stats
    {
        float4 s1 = {0, 0, 0, 0}, s2 = {0, 0, 0, 0};
        #pragma unroll 4
        for (int c = 0; c < 192; c += 8) {
            float4 v = *(const float4*)(base + (long)c * 16384);
            s1.x += v.x; s1.y += v.y; s1.z += v.z; s1.w += v.w;
            s2.x += v.x * v.x; s2.y += v.y * v.y; s2.z += v.z * v.z; s2.w += v.w * v.w;
        }
        *(float4*)&p1[cg][4 * w4] = s1;
        *(float4*)&p2[cg][4 * w4] = s2;
    }
    __syncthreads();
    if (tid < 128) {
        float a = 0.f, q = 0.f;
        #pragma unroll
        for (int g = 0; g < 8; ++g) { a += p1[g][tid]; q += p2[g][tid]; }
        float mu = a * (1.0f / 192.0f);
        float var = q * (1.0f / 192.0f) - mu * mu;
        mu_s[tid] = mu; rs_s[tid] = rsqrtf(var + EPS);
    }
    __syncthreads();

    // ---- pass 2: re-read (L2-hot), normalize, bf16 -> LDS
    {
        float mu0 = mu_s[4 * w4 + 0], rs0 = rs_s[4 * w4 + 0];
        float mu1 = mu_s[4 * w4 + 1], rs1 = rs_s[4 * w4 + 1];
        float mu2 = mu_s[4 * w4 + 2], rs2 = rs_s[4 * w4 + 2];
        float mu3 = mu_s[4 * w4 + 3], rs3 = rs_s[4 * w4 + 3];
        #pragma unroll 4
        for (int c = cg; c < 192; c += 8) {
            float4 v = *(const float4*)(base + (long)(c - cg) * 16384);
            float g = gb[c], be = gb[192 + c];
            lxs[(4 * w4 + 0) * 200 + c] = f2bf((v.x - mu0) * rs0 * g + be);
            lxs[(4 * w4 + 1) * 200 + c] = f2bf((v.y - mu1) * rs1 * g + be);
            lxs[(4 * w4 + 2) * 200 + c] = f2bf((v.z - mu2) * rs2 * g + be);
            lxs[(4 * w4 + 3) * 200 + c] = f2bf((v.w - mu3) * rs3 * g + be);
        }
    }
    __syncthreads();

    // ---- write rows coalesced: lxg[b][h*128 + px][192]
    {
        const int px = tid >> 1, part = tid & 1;
        u16* dst = lxg + (((long)b << 14) + h * 128 + px) * 192 + 96 * part;
        const u16* src = &lxs[px * 200 + 96 * part];
        #pragma unroll
        for (int i = 0; i < 12; ++i)
            *(u16x8*)(dst + 8 * i) = *(const u16x8*)(src + 8 * i);
    }
}

// ---------------- kernel 2: QKV GEMM from lxg. 1536 blocks x 512 threads.
// job 0: Q -> qk_g[pix][0..192); job 1: K -> qk_g[pix][192..384); job 2: V -> vT_g[o][pix]
__launch_bounds__(512, 2)
__global__ void qkv_kernel(const u16* __restrict__ lxg, const u16* __restrict__ wbf,
                           u16* __restrict__ qk_g, u16* __restrict__ vT_g) {
    __shared__ u16 lx[128 * 200];           // [token][c]

    const int tid = threadIdx.x;
    const int job = blockIdx.x >> 9;         // 0,1,2
    const int tile = blockIdx.x & 511;
    const int b = tile >> 7;
    const int hw0 = (tile & 127) * 128;

    // ---- stage 128 rows of lxg into LDS (coalesced u16x8)
    {
        const int px = tid >> 2, seg = tid & 3;
        const u16* src = lxg + (((long)b << 14) + hw0 + px) * 192 + 48 * seg;
        u16* dst = &lx[px * 200 + 48 * seg];
        #pragma unroll
        for (int i = 0; i < 6; ++i)
            *(u16x8*)(dst + 8 * i) = *(const u16x8*)(src + 8 * i);
    }
    __syncthreads();

    const int wv_ = tid >> 6, lane = tid & 63;
    const int l15 = lane & 15, g4 = lane >> 4;
    const u16* wsrc = wbf + job * 36864;

    if (job < 2) {
        // out[s][o] = lx . W^T ; wave owns m-tile wv_ (16 px), 12 o-tiles
        const int obase = job * 192;
        const long rowb = ((long)b << 14) + hw0;
        for (int ntp = 0; ntp < 12; ++ntp) {
            f32x4 acc = {};
            #pragma unroll
            for (int ks = 0; ks < 6; ++ks) {
                bf16x8v a = *(const bf16x8v*)&lx[(16 * wv_ + l15) * 200 + 32 * ks + 8 * g4];
                bf16x8v bb = *(const bf16x8v*)&wsrc[(16 * ntp + l15) * 192 + 32 * ks + 8 * g4];
                acc = mfma16(a, bb, acc);           // D: row=s, col=o
            }
            const int o = 16 * ntp + l15;
            #pragma unroll
            for (int r = 0; r < 4; ++r) {
                int s = 16 * wv_ + 4 * g4 + r;
                qk_g[(rowb + s) * 384 + obase + o] = f2bf(acc[r]);
            }
        }
    } else {
        // out[o][s] = W . lx^T ; wave owns s-tile wv_ (16 px), 12 o-tiles
        for (int ot = 0; ot < 12; ++ot) {
            f32x4 acc = {};
            #pragma unroll
            for (int ks = 0; ks < 6; ++ks) {
                bf16x8v a = *(const bf16x8v*)&wsrc[(16 * ot + l15) * 192 + 32 * ks + 8 * g4];
                bf16x8v bb = *(const bf16x8v*)&lx[(16 * wv_ + l15) * 200 + 32 * ks + 8 * g4];
                acc = mfma16(a, bb, acc);           // D: row=o, col=s
            }
            const int s = 16 * wv_ + l15;
            #pragma unroll
            for (int r = 0; r < 4; ++r) {
                int o = 16 * ot + 4 * g4 + r;
                vT_g[(((long)(b * 192 + o)) << 14) + hw0 + s] = f2bf(acc[r]);
            }
        }
    }
}

// ---------------- kernel 3: per (window, head) attention. 512 threads (8 waves).
// LDS: Q[256][40] + K[256][40] (P[256][72] overlays Q+K) + VT[32][264]
__launch_bounds__(512, 2)
__global__ void attn_kernel(const u16* __restrict__ qk_g, const u16* __restrict__ vT_g,
                            float* __restrict__ out_win) {
    __shared__ u16 smem[28928];
    u16* Qs = smem;            // [256][40]
    u16* Ks = smem + 10240;    // [256][40]
    u16* Ps = smem;            // overlay [256][72]
    u16* Vs = smem + 20480;    // [32][264]

    const int tid = threadIdx.x;
    const int win = blockIdx.x / 6, h = blockIdx.x % 6;
    const int b = win / NWIN, wi = win % NWIN;
    const int t0 = 14 * (wi / 9), l0 = 14 * (wi % 9);

    { // stage Q,K head-slices [256][32] and V^T slice [32][256]
        int s = tid >> 1, hf = tid & 1;
        int p = (t0 + (s >> 4)) * 128 + l0 + (s & 15);
        const u16* src = qk_g + (((long)b << 14) + p) * 384 + 32 * h + 16 * hf;
        *(u16x8*)&Qs[s * 40 + 16 * hf    ] = *(const u16x8*)(src);
        *(u16x8*)&Qs[s * 40 + 16 * hf + 8] = *(const u16x8*)(src + 8);
        *(u16x8*)&Ks[s * 40 + 16 * hf    ] = *(const u16x8*)(src + 192);
        *(u16x8*)&Ks[s * 40 + 16 * hf + 8] = *(const u16x8*)(src + 200);

        int r = tid >> 4, seg = tid & 15;
        const u16* vsrc = vT_g + (((long)(b * 192 + 32 * h + r)) << 14) + (t0 + seg) * 128 + l0;
        #pragma unroll
        for (int j = 0; j < 16; ++j)
            Vs[r * 264 + 16 * seg + j] = vsrc[j];
    }
    __syncthreads();

    const int lane = tid & 63, wv_ = tid >> 6;
    const int l15 = lane & 15, g4 = lane >> 4;

    // scoresT[key][q] = K . Q^T ; wave owns q-tiles {2wv_, 2wv_+1}
    f32x4 sc[16][2];
    {
        bf16x8v bq0 = *(const bf16x8v*)&Qs[(16 * (2 * wv_ + 0) + l15) * 40 + 8 * g4];
        bf16x8v bq1 = *(const bf16x8v*)&Qs[(16 * (2 * wv_ + 1) + l15) * 40 + 8 * g4];
        const f32x4 z = {0.f, 0.f, 0.f, 0.f};
        #pragma unroll
        for (int mt = 0; mt < 16; ++mt) {
            bf16x8v a = *(const bf16x8v*)&Ks[(16 * mt + l15) * 40 + 8 * g4];
            sc[mt][0] = mfma16(a, bq0, z);
            sc[mt][1] = mfma16(a, bq1, z);
        }
    }

    // softmax over keys: lane-local 64 vals + xor16 + xor32
    float rden[2];
    #pragma unroll
    for (int nq = 0; nq < 2; ++nq) {
        float mx = -1e30f;
        #pragma unroll
        for (int mt = 0; mt < 16; ++mt)
            #pragma unroll
            for (int r = 0; r < 4; ++r) mx = fmaxf(mx, sc[mt][nq][r]);
        mx = fmaxf(mx, __shfl_xor(mx, 16, 64));
        mx = fmaxf(mx, __shfl_xor(mx, 32, 64));
        float sum = 0.f;
        #pragma unroll
        for (int mt = 0; mt < 16; ++mt)
            #pragma unroll
            for (int r = 0; r < 4; ++r) {
                float p = __expf((sc[mt][nq][r] - mx) * SCALE);
                sc[mt][nq][r] = p; sum += p;
            }
        sum += __shfl_xor(sum, 16, 64);
        sum += __shfl_xor(sum, 32, 64);
        rden[nq] = 1.0f / sum;
    }

    // PV: outT[dv][q] = V^T . P^T, P staged per 64-key chunk (Ps overlays Q/K)
    f32x4 oacc[2][2] = {};
    #pragma unroll
    for (int kc = 0; kc < 4; ++kc) {
        __syncthreads();   // prior readers of Ps region (or Q/K reads at kc=0) done
        #pragma unroll
        for (int mtl = 0; mtl < 4; ++mtl) {
            int mt = 4 * kc + mtl;
            #pragma unroll
            for (int nq = 0; nq < 2; ++nq) {
                int q = 16 * (2 * wv_ + nq) + l15;
                u16x4 pk = { f2bf(sc[mt][nq][0]), f2bf(sc[mt][nq][1]),
                             f2bf(sc[mt][nq][2]), f2bf(sc[mt][nq][3]) };
                *(u16x4*)&Ps[q * 72 + 16 * mtl + 4 * g4] = pk;
            }
        }
        __syncthreads();
        #pragma unroll
        for (int ksl = 0; ksl < 2; ++ksl) {
            bf16x8v a0 = *(const bf16x8v*)&Vs[(l15) * 264 + 64 * kc + 32 * ksl + 8 * g4];
            bf16x8v a1 = *(const bf16x8v*)&Vs[(16 + l15) * 264 + 64 * kc + 32 * ksl + 8 * g4];
            bf16x8v b0 = *(const bf16x8v*)&Ps[(16 * (2 * wv_ + 0) + l15) * 72 + 32 * ksl + 8 * g4];
            bf16x8v b1 = *(const bf16x8v*)&Ps[(16 * (2 * wv_ + 1) + l15) * 72 + 32 * ksl + 8 * g4];
            oacc[0][0] = mfma16(a0, b0, oacc[0][0]); oacc[0][1] = mfma16(a0, b1, oacc[0][1]);
            oacc[1][0] = mfma16(a1, b0, oacc[1][0]); oacc[1][1] = mfma16(a1, b1, oacc[1][1]);
        }
    }

    // epilogue: divide by denom, write out_win[win][c][s]
    #pragma unroll
    for (int mtv = 0; mtv < 2; ++mtv)
        #pragma unroll
        for (int nq = 0; nq < 2; ++nq)
            #pragma unroll
            for (int r = 0; r < 4; ++r) {
                int c = 32 * h + 16 * mtv + 4 * g4 + r;
                int q = 16 * (2 * wv_ + nq) + l15;
                out_win[((long)win * 192 + c) * 256 + q] = oacc[mtv][nq][r] * rden[nq];
            }
}

// ---------------- kernel 4: overlap-add gather + divide by COUNT
__global__ void gather_kernel(const float* __restrict__ out_win, float* __restrict__ out) {
    int idx = blockIdx.x * 256 + threadIdx.x;       // 12,582,912 exact
    int w = idx & 127, hh = (idx >> 7) & 127;
    int v = idx >> 14; int c = v % 192, b = v / 192;
    int khmin = (hh - 2) / 14; if (khmin < 0) khmin = 0;
    int khmax = hh / 14; if (khmax > 8) khmax = 8;
    int kwmin = (w - 2) / 14; if (kwmin < 0) kwmin = 0;
    int kwmax = w / 14; if (kwmax > 8) kwmax = 8;
    float acc = 0.f; int cnt = 0;
    for (int ih = khmin; ih <= khmax; ++ih)
        for (int iw = kwmin; iw <= kwmax; ++iw) {
            int win = b * NWIN + ih * 9 + iw;
            int s = (hh - 14 * ih) * 16 + (w - 14 * iw);
            acc += out_win[((long)win * 192 + c) * 256 + s];
            ++cnt;
        }
    float rc = (cnt == 1) ? 1.0f : (cnt == 2 ? 0.5f : 0.25f);  // cnt in {1,2,4}
    out[idx] = acc * rc;
}

extern "C" void kernel_launch(void* const* d_in, const int* in_sizes, int n_in,
                              void* d_out, int out_size, void* d_ws, size_t ws_size,
                              hipStream_t stream) {
    const float* x     = (const float*)d_in[0];
    const float* Wq    = (const float*)d_in[1];
    const float* Wk    = (const float*)d_in[2];
    const float* Wv    = (const float*)d_in[3];
    const float* gamma = (const float*)d_in[4];
    const float* beta  = (const float*)d_in[5];

    char* ws = (char*)d_ws;
    // layout: wbf 221184 | qk_g 50331648 | vT_g 25165824 | X (lxg 25165824 OVERLAYS out_win 63700992)
    // lxg lifetime: lnx(W) -> qkv(R).  out_win lifetime: attn(W) -> gather(R).  Disjoint. Total 139.4 MB.
    u16*   wbf     = (u16*)ws;
    u16*   qk_g    = (u16*)(ws + 221184);
    u16*   vT_g    = (u16*)(ws + 221184 + 50331648L);
    u16*   lxg     = (u16*)(ws + 221184 + 75497472L);
    float* out_win = (float*)(ws + 221184 + 75497472L);

    wconv<<<dim3(432), dim3(256), 0, stream>>>(Wq, Wk, Wv, wbf);
    lnx_kernel<<<dim3(512), dim3(256), 0, stream>>>(x, gamma, beta, lxg);
    qkv_kernel<<<dim3(1536), dim3(512), 0, stream>>>(lxg, wbf, qk_g, vT_g);
    attn_kernel<<<dim3(BN * 6), dim3(512), 0, stream>>>(qk_g, vT_g, out_win);
    gather_kernel<<<dim3(49152), dim3(256), 0, stream>>>(out_win, (float*)d_out);
}

// Round 7
// 193.209 us; speedup vs baseline: 1.3744x; 1.3744x over previous
//
#include <hip/hip_runtime.h>
#include <stdint.h>

#define DEV __device__ __forceinline__

typedef unsigned short u16;
typedef u16   u16x8 __attribute__((ext_vector_type(8)));
typedef u16   u16x4 __attribute__((ext_vector_type(4)));
typedef u16   u16x2 __attribute__((ext_vector_type(2)));
typedef __bf16 bf16x8v __attribute__((ext_vector_type(8)));
typedef float f32x4 __attribute__((ext_vector_type(4)));

constexpr int NWIN = 81;          // 9x9 windows per batch
constexpr int BN   = 4 * NWIN;    // 324 total windows
constexpr float EPS = 1e-5f;
constexpr float SCALE = 0.07216878364870322f; // 192^-0.5

DEV u16 f2bf(float f) {            // fp32 -> bf16 RNE
    unsigned u = __builtin_bit_cast(unsigned, f);
    u += 0x7fffu + ((u >> 16) & 1u);
    return (u16)(u >> 16);
}

DEV f32x4 mfma16(bf16x8v a, bf16x8v b, f32x4 c) {
    return __builtin_amdgcn_mfma_f32_16x16x32_bf16(a, b, c, 0, 0, 0);
}

// ---------------- kernel 0: convert Wq|Wk|Wv fp32 -> bf16 (contiguous in ws)
__global__ void wconv(const float* __restrict__ wq, const float* __restrict__ wk,
                      const float* __restrict__ wv, u16* __restrict__ dst) {
    int idx = blockIdx.x * 256 + threadIdx.x;       // 3*36864 exact
    const float* src = (idx < 36864) ? wq : (idx < 73728 ? wk : wv);
    int r = (idx < 36864) ? idx : (idx < 73728 ? idx - 36864 : idx - 73728);
    dst[idx] = f2bf(src[r]);
}

// ---------------- kernel 1: LN stats + normalize -> lxg bf16 [b][pix][192]
__global__ void lnx_kernel(const float* __restrict__ x, const float* __restrict__ gamma,
                           const float* __restrict__ beta, u16* __restrict__ lxg) {
    __shared__ float p1[8][132], p2[8][132];
    __shared__ float gb[384];
    __shared__ float mu_s[128], rs_s[128];
    __shared__ u16 lxs[128 * 200];

    const int bh = blockIdx.x;               // 0..511
    const int b = bh >> 7, h = bh & 127;
    const int tid = threadIdx.x;
    const int w4 = tid & 31, cg = tid >> 5;  // 32 pixel-quads x 8 channel groups

    if (tid < 192) { gb[tid] = gamma[tid]; gb[192 + tid] = beta[tid]; }

    const float* base = x + (((long)(b * 192 + cg)) * 128 + h) * 128 + 4 * w4;
    // ---- pass 1: stats
    {
        float4 s1 = {0, 0, 0, 0}, s2 = {0, 0, 0, 0};
        #pragma unroll 4
        for (int c = 0; c < 192; c += 8) {
            float4 v = *(const float4*)(base + (long)c * 16384);
            s1.x += v.x; s1.y += v.y; s1.z += v.z; s1.w += v.w;
            s2.x += v.x * v.x; s2.y += v.y * v.y; s2.z += v.z * v.z; s2.w += v.w * v.w;
        }
        *(float4*)&p1[cg][4 * w4] = s1;
        *(float4*)&p2[cg][4 * w4] = s2;
    }
    __syncthreads();
    if (tid < 128) {
        float a = 0.f, q = 0.f;
        #pragma unroll
        for (int g = 0; g < 8; ++g) { a += p1[g][tid]; q += p2[g][tid]; }
        float mu = a * (1.0f / 192.0f);
        float var = q * (1.0f / 192.0f) - mu * mu;
        mu_s[tid] = mu; rs_s[tid] = rsqrtf(var + EPS);
    }
    __syncthreads();

    // ---- pass 2: re-read (L2-hot), normalize, bf16 -> LDS
    {
        float mu0 = mu_s[4 * w4 + 0], rs0 = rs_s[4 * w4 + 0];
        float mu1 = mu_s[4 * w4 + 1], rs1 = rs_s[4 * w4 + 1];
        float mu2 = mu_s[4 * w4 + 2], rs2 = rs_s[4 * w4 + 2];
        float mu3 = mu_s[4 * w4 + 3], rs3 = rs_s[4 * w4 + 3];
        #pragma unroll 4
        for (int c = cg; c < 192; c += 8) {
            float4 v = *(const float4*)(base + (long)(c - cg) * 16384);
            float g = gb[c], be = gb[192 + c];
            lxs[(4 * w4 + 0) * 200 + c] = f2bf((v.x - mu0) * rs0 * g + be);
            lxs[(4 * w4 + 1) * 200 + c] = f2bf((v.y - mu1) * rs1 * g + be);
            lxs[(4 * w4 + 2) * 200 + c] = f2bf((v.z - mu2) * rs2 * g + be);
            lxs[(4 * w4 + 3) * 200 + c] = f2bf((v.w - mu3) * rs3 * g + be);
        }
    }
    __syncthreads();

    // ---- write rows coalesced: lxg[b][h*128 + px][192]
    {
        const int px = tid >> 1, part = tid & 1;
        u16* dst = lxg + (((long)b << 14) + h * 128 + px) * 192 + 96 * part;
        const u16* src = &lxs[px * 200 + 96 * part];
        #pragma unroll
        for (int i = 0; i < 12; ++i)
            *(u16x8*)(dst + 8 * i) = *(const u16x8*)(src + 8 * i);
    }
}

// ---------------- kernel 2: QKV GEMM from lxg. 1536 blocks x 256 threads (4 waves).
// Wave register-caches its 3 o-tiles of W (18 bf16x8), owns all 8 m-tiles.
// job 0: Q -> qk_g[pix][0..192); job 1: K -> qk_g[pix][192..384); job 2: V -> vT_g[o][pix]
__launch_bounds__(256, 3)
__global__ void qkv_kernel(const u16* __restrict__ lxg, const u16* __restrict__ wbf,
                           u16* __restrict__ qk_g, u16* __restrict__ vT_g) {
    __shared__ u16 lx[128 * 200];           // [token][c]

    const int tid = threadIdx.x;
    const int job = blockIdx.x >> 9;         // 0,1,2
    const int tile = blockIdx.x & 511;
    const int b = tile >> 7;
    const int hw0 = (tile & 127) * 128;

    // ---- stage 128 rows of lxg into LDS (coalesced u16x8)
    {
        const int px = tid >> 1, part = tid & 1;
        const u16* src = lxg + (((long)b << 14) + hw0 + px) * 192 + 96 * part;
        u16* dst = &lx[px * 200 + 96 * part];
        #pragma unroll
        for (int i = 0; i < 12; ++i)
            *(u16x8*)(dst + 8 * i) = *(const u16x8*)(src + 8 * i);
    }

    const int wv_ = tid >> 6, lane = tid & 63;
    const int l15 = lane & 15, g4 = lane >> 4;
    const u16* wsrc = wbf + job * 36864;

    // ---- preload B fragments (W rows) into registers while barrier pends
    bf16x8v B[3][6];
    #pragma unroll
    for (int oi = 0; oi < 3; ++oi)
        #pragma unroll
        for (int ks = 0; ks < 6; ++ks)
            B[oi][ks] = *(const bf16x8v*)&wsrc[(16 * (3 * wv_ + oi) + l15) * 192 + 32 * ks + 8 * g4];

    __syncthreads();

    if (job < 2) {
        // out[s][o] = lx . W^T ; D: row=s (4*g4+r), col=o (l15)
        const int obase = job * 192;
        const long rowb = ((long)b << 14) + hw0;
        #pragma unroll 1
        for (int m = 0; m < 8; ++m) {
            bf16x8v A[6];
            #pragma unroll
            for (int ks = 0; ks < 6; ++ks)
                A[ks] = *(const bf16x8v*)&lx[(16 * m + l15) * 200 + 32 * ks + 8 * g4];
            f32x4 acc[3] = {};
            #pragma unroll
            for (int ks = 0; ks < 6; ++ks)
                #pragma unroll
                for (int oi = 0; oi < 3; ++oi)
                    acc[oi] = mfma16(A[ks], B[oi][ks], acc[oi]);
            #pragma unroll
            for (int oi = 0; oi < 3; ++oi) {
                const int o = obase + 16 * (3 * wv_ + oi) + l15;
                #pragma unroll
                for (int r = 0; r < 4; ++r)
                    qk_g[(rowb + 16 * m + 4 * g4 + r) * 384 + o] = f2bf(acc[oi][r]);
            }
        }
    } else {
        // out[o][s] = W . lx^T ; D: row=o (4*g4+r), col=s (l15)
        #pragma unroll 1
        for (int m = 0; m < 8; ++m) {
            bf16x8v A[6];
            #pragma unroll
            for (int ks = 0; ks < 6; ++ks)
                A[ks] = *(const bf16x8v*)&lx[(16 * m + l15) * 200 + 32 * ks + 8 * g4];
            f32x4 acc[3] = {};
            #pragma unroll
            for (int ks = 0; ks < 6; ++ks)
                #pragma unroll
                for (int oi = 0; oi < 3; ++oi)
                    acc[oi] = mfma16(B[oi][ks], A[ks], acc[oi]);
            #pragma unroll
            for (int oi = 0; oi < 3; ++oi)
                #pragma unroll
                for (int r = 0; r < 4; ++r) {
                    const int o = 16 * (3 * wv_ + oi) + 4 * g4 + r;
                    vT_g[(((long)(b * 192 + o)) << 14) + hw0 + 16 * m + l15] = f2bf(acc[oi][r]);
                }
        }
    }
}

// ---------------- kernel 3: per (window, head) attention. 512 threads (8 waves).
// LDS: Q[256][40] + K[256][40] (P[256][72] overlays Q+K) + VT[32][264]
__launch_bounds__(512, 2)
__global__ void attn_kernel(const u16* __restrict__ qk_g, const u16* __restrict__ vT_g,
                            float* __restrict__ out_win) {
    __shared__ u16 smem[28928];
    u16* Qs = smem;            // [256][40]
    u16* Ks = smem + 10240;    // [256][40]
    u16* Ps = smem;            // overlay [256][72]
    u16* Vs = smem + 20480;    // [32][264]

    const int tid = threadIdx.x;
    const int win = blockIdx.x / 6, h = blockIdx.x % 6;
    const int b = win / NWIN, wi = win % NWIN;
    const int t0 = 14 * (wi / 9), l0 = 14 * (wi % 9);

    { // stage Q,K head-slices [256][32] and V^T slice [32][256]
        int s = tid >> 1, hf = tid & 1;
        int p = (t0 + (s >> 4)) * 128 + l0 + (s & 15);
        const u16* src = qk_g + (((long)b << 14) + p) * 384 + 32 * h + 16 * hf;
        *(u16x8*)&Qs[s * 40 + 16 * hf    ] = *(const u16x8*)(src);
        *(u16x8*)&Qs[s * 40 + 16 * hf + 8] = *(const u16x8*)(src + 8);
        *(u16x8*)&Ks[s * 40 + 16 * hf    ] = *(const u16x8*)(src + 192);
        *(u16x8*)&Ks[s * 40 + 16 * hf + 8] = *(const u16x8*)(src + 200);

        // V: 4096 u16x2 chunks; lanes run along pixels for contiguous 32B sectors
        #pragma unroll
        for (int j = 0; j < 8; ++j) {
            int gid = j * 512 + tid;
            int o = gid >> 7, rq = gid & 127, run = rq >> 3, q = rq & 7;
            const u16* vsrc = vT_g + (((long)(b * 192 + 32 * h + o)) << 14)
                              + (t0 + run) * 128 + l0 + 2 * q;
            *(u16x2*)&Vs[o * 264 + run * 16 + 2 * q] = *(const u16x2*)vsrc;
        }
    }
    __syncthreads();

    const int lane = tid & 63, wv_ = tid >> 6;
    const int l15 = lane & 15, g4 = lane >> 4;

    // scoresT[key][q] = K . Q^T ; wave owns q-tiles {2wv_, 2wv_+1}
    f32x4 sc[16][2];
    {
        bf16x8v bq0 = *(const bf16x8v*)&Qs[(16 * (2 * wv_ + 0) + l15) * 40 + 8 * g4];
        bf16x8v bq1 = *(const bf16x8v*)&Qs[(16 * (2 * wv_ + 1) + l15) * 40 + 8 * g4];
        const f32x4 z = {0.f, 0.f, 0.f, 0.f};
        #pragma unroll
        for (int mt = 0; mt < 16; ++mt) {
            bf16x8v a = *(const bf16x8v*)&Ks[(16 * mt + l15) * 40 + 8 * g4];
            sc[mt][0] = mfma16(a, bq0, z);
            sc[mt][1] = mfma16(a, bq1, z);
        }
    }

    // softmax over keys: lane-local 64 vals + xor16 + xor32
    float rden[2];
    #pragma unroll
    for (int nq = 0; nq < 2; ++nq) {
        float mx = -1e30f;
        #pragma unroll
        for (int mt = 0; mt < 16; ++mt)
            #pragma unroll
            for (int r = 0; r < 4; ++r) mx = fmaxf(mx, sc[mt][nq][r]);
        mx = fmaxf(mx, __shfl_xor(mx, 16, 64));
        mx = fmaxf(mx, __shfl_xor(mx, 32, 64));
        float sum = 0.f;
        #pragma unroll
        for (int mt = 0; mt < 16; ++mt)
            #pragma unroll
            for (int r = 0; r < 4; ++r) {
                float p = __expf((sc[mt][nq][r] - mx) * SCALE);
                sc[mt][nq][r] = p; sum += p;
            }
        sum += __shfl_xor(sum, 16, 64);
        sum += __shfl_xor(sum, 32, 64);
        rden[nq] = 1.0f / sum;
    }

    // PV: outT[dv][q] = V^T . P^T, P staged per 64-key chunk (Ps overlays Q/K)
    f32x4 oacc[2][2] = {};
    #pragma unroll
    for (int kc = 0; kc < 4; ++kc) {
        __syncthreads();   // prior readers of Ps region (or Q/K reads at kc=0) done
        #pragma unroll
        for (int mtl = 0; mtl < 4; ++mtl) {
            int mt = 4 * kc + mtl;
            #pragma unroll
            for (int nq = 0; nq < 2; ++nq) {
                int q = 16 * (2 * wv_ + nq) + l15;
                u16x4 pk = { f2bf(sc[mt][nq][0]), f2bf(sc[mt][nq][1]),
                             f2bf(sc[mt][nq][2]), f2bf(sc[mt][nq][3]) };
                *(u16x4*)&Ps[q * 72 + 16 * mtl + 4 * g4] = pk;
            }
        }
        __syncthreads();
        #pragma unroll
        for (int ksl = 0; ksl < 2; ++ksl) {
            bf16x8v a0 = *(const bf16x8v*)&Vs[(l15) * 264 + 64 * kc + 32 * ksl + 8 * g4];
            bf16x8v a1 = *(const bf16x8v*)&Vs[(16 + l15) * 264 + 64 * kc + 32 * ksl + 8 * g4];
            bf16x8v b0 = *(const bf16x8v*)&Ps[(16 * (2 * wv_ + 0) + l15) * 72 + 32 * ksl + 8 * g4];
            bf16x8v b1 = *(const bf16x8v*)&Ps[(16 * (2 * wv_ + 1) + l15) * 72 + 32 * ksl + 8 * g4];
            oacc[0][0] = mfma16(a0, b0, oacc[0][0]); oacc[0][1] = mfma16(a0, b1, oacc[0][1]);
            oacc[1][0] = mfma16(a1, b0, oacc[1][0]); oacc[1][1] = mfma16(a1, b1, oacc[1][1]);
        }
    }

    // epilogue: divide by denom, write out_win[win][c][s]
    #pragma unroll
    for (int mtv = 0; mtv < 2; ++mtv)
        #pragma unroll
        for (int nq = 0; nq < 2; ++nq)
            #pragma unroll
            for (int r = 0; r < 4; ++r) {
                int c = 32 * h + 16 * mtv + 4 * g4 + r;
                int q = 16 * (2 * wv_ + nq) + l15;
                out_win[((long)win * 192 + c) * 256 + q] = oacc[mtv][nq][r] * rden[nq];
            }
}

// ---------------- kernel 4: overlap-add gather + divide by COUNT
__global__ void gather_kernel(const float* __restrict__ out_win, float* __restrict__ out) {
    int idx = blockIdx.x * 256 + threadIdx.x;       // 12,582,912 exact
    int w = idx & 127, hh = (idx >> 7) & 127;
    int v = idx >> 14; int c = v % 192, b = v / 192;
    int khmin = (hh - 2) / 14; if (khmin < 0) khmin = 0;
    int khmax = hh / 14; if (khmax > 8) khmax = 8;
    int kwmin = (w - 2) / 14; if (kwmin < 0) kwmin = 0;
    int kwmax = w / 14; if (kwmax > 8) kwmax = 8;
    float acc = 0.f; int cnt = 0;
    for (int ih = khmin; ih <= khmax; ++ih)
        for (int iw = kwmin; iw <= kwmax; ++iw) {
            int win = b * NWIN + ih * 9 + iw;
            int s = (hh - 14 * ih) * 16 + (w - 14 * iw);
            acc += out_win[((long)win * 192 + c) * 256 + s];
            ++cnt;
        }
    float rc = (cnt == 1) ? 1.0f : (cnt == 2 ? 0.5f : 0.25f);  // cnt in {1,2,4}
    out[idx] = acc * rc;
}

extern "C" void kernel_launch(void* const* d_in, const int* in_sizes, int n_in,
                              void* d_out, int out_size, void* d_ws, size_t ws_size,
                              hipStream_t stream) {
    const float* x     = (const float*)d_in[0];
    const float* Wq    = (const float*)d_in[1];
    const float* Wk    = (const float*)d_in[2];
    const float* Wv    = (const float*)d_in[3];
    const float* gamma = (const float*)d_in[4];
    const float* beta  = (const float*)d_in[5];

    char* ws = (char*)d_ws;
    // layout: wbf 221184 | qk_g 50331648 | vT_g 25165824 | X (lxg 25165824 OVERLAYS out_win 63700992)
    // lxg lifetime: lnx(W) -> qkv(R).  out_win lifetime: attn(W) -> gather(R).  Disjoint.
    u16*   wbf     = (u16*)ws;
    u16*   qk_g    = (u16*)(ws + 221184);
    u16*   vT_g    = (u16*)(ws + 221184 + 50331648L);
    u16*   lxg     = (u16*)(ws + 221184 + 75497472L);
    float* out_win = (float*)(ws + 221184 + 75497472L);

    wconv<<<dim3(432), dim3(256), 0, stream>>>(Wq, Wk, Wv, wbf);
    lnx_kernel<<<dim3(512), dim3(256), 0, stream>>>(x, gamma, beta, lxg);
    qkv_kernel<<<dim3(1536), dim3(256), 0, stream>>>(lxg, wbf, qk_g, vT_g);
    attn_kernel<<<dim3(BN * 6), dim3(512), 0, stream>>>(qk_g, vT_g, out_win);
    gather_kernel<<<dim3(49152), dim3(256), 0, stream>>>(out_win, (float*)d_out);
}